// Round 1
// baseline (515.841 us; speedup 1.0000x reference)
//
#include <hip/hip_runtime.h>
#include <math.h>

#define TOKENS 16384
#define DMODEL 2048
#define NEXP   256
#define TOPK   8
#define BM     32
#define BK     16

// ---------------- transpose gate_w (E x D) -> wT (D x E) ----------------
__global__ void k_transpose(const float* __restrict__ w, float* __restrict__ wT) {
    int g = blockIdx.x * 256 + threadIdx.x;      // over D*E, write-coalesced
    int d = g >> 8;
    int e = g & 255;
    wT[g] = w[(size_t)e * DMODEL + d];
}

// ---------------- zero the counts region of d_out ----------------
__global__ void k_zero(float* __restrict__ counts) {
    counts[threadIdx.x] = 0.0f;
}

// ---------------- main: GEMM + bias + top-8 + softmax + histogram ----------------
__global__ __launch_bounds__(256, 3) void k_main(
        const float* __restrict__ x,
        const float* __restrict__ wsrc,       // wT (DxE) if transposed, else w (ExD)
        const float* __restrict__ bias,
        float* __restrict__ out,
        int transposed) {
    __shared__ float xT[BK][BM];          // 2 KB, [k][tok]
    __shared__ float wS[BK][NEXP];        // 16 KB, [k][e]
    __shared__ float logits[BM][NEXP];    // 32 KB
    __shared__ float hist[NEXP];          // 1 KB

    const int tid  = threadIdx.x;
    const int tok0 = blockIdx.x * BM;
    const int ty   = tid >> 5;            // 0..7  -> tokens ty*4 .. ty*4+3
    const int tx   = tid & 31;            // 0..31 -> experts tx*8 .. tx*8+7

    hist[tid] = 0.0f;

    float acc[4][8];
#pragma unroll
    for (int i = 0; i < 4; i++)
#pragma unroll
        for (int j = 0; j < 8; j++) acc[i][j] = 0.0f;

    // x staging map: one float2 per thread
    const int lx_tok = tid >> 3;          // 0..31
    const int lx_d   = (tid & 7) * 2;     // 0,2,..,14

    for (int k0 = 0; k0 < DMODEL; k0 += BK) {
        __syncthreads();
        // stage x chunk (32 tok x 16 d), transposed into LDS
        float2 xv = *(const float2*)&x[(size_t)(tok0 + lx_tok) * DMODEL + k0 + lx_d];
        xT[lx_d][lx_tok]     = xv.x;
        xT[lx_d + 1][lx_tok] = xv.y;
        // stage w chunk (16 d x 256 e)
        if (transposed) {
#pragma unroll
            for (int i = 0; i < BK; i++)
                wS[i][tid] = wsrc[(size_t)(k0 + i) * NEXP + tid];
        } else {
#pragma unroll
            for (int i = 0; i < BK; i++)
                wS[i][tid] = wsrc[(size_t)tid * DMODEL + k0 + i];
        }
        __syncthreads();
#pragma unroll
        for (int k = 0; k < BK; k++) {
            float4 a  = *(const float4*)&xT[k][ty * 4];
            float4 b0 = *(const float4*)&wS[k][tx * 8];
            float4 b1 = *(const float4*)&wS[k][tx * 8 + 4];
            float av[4] = {a.x, a.y, a.z, a.w};
            float bv[8] = {b0.x, b0.y, b0.z, b0.w, b1.x, b1.y, b1.z, b1.w};
#pragma unroll
            for (int i = 0; i < 4; i++)
#pragma unroll
                for (int j = 0; j < 8; j++)
                    acc[i][j] = fmaf(av[i], bv[j], acc[i][j]);
        }
    }

    // bias add, write logits to LDS
    float bb[8];
#pragma unroll
    for (int j = 0; j < 8; j++) bb[j] = bias[tx * 8 + j];
#pragma unroll
    for (int i = 0; i < 4; i++) {
#pragma unroll
        for (int j = 0; j < 8; j++)
            logits[ty * 4 + i][tx * 8 + j] = acc[i][j] + bb[j];
    }
    __syncthreads();

    // ---- top-8 per token; each wave handles 8 tokens ----
    const int lane = tid & 63;
    const int wv   = tid >> 6;            // 0..3
    for (int tt = 0; tt < 8; tt++) {
        const int tok = wv * 8 + tt;
        float4 v4 = *(const float4*)&logits[tok][lane * 4];
        float lv[4] = {v4.x, v4.y, v4.z, v4.w};
        int msk = 0xF;
        float topv[TOPK];
        int   topi[TOPK];
#pragma unroll
        for (int r = 0; r < TOPK; r++) {
            float bvv = -INFINITY;
            int   bii = 0x7fffffff;
#pragma unroll
            for (int j = 0; j < 4; j++) {
                if (msk & (1 << j)) {
                    float vv = lv[j];
                    int   ii = lane * 4 + j;
                    if (vv > bvv || (vv == bvv && ii < bii)) { bvv = vv; bii = ii; }
                }
            }
            // 64-lane butterfly argmax, ties -> lowest index (jax top_k semantics)
#pragma unroll
            for (int off = 32; off > 0; off >>= 1) {
                float ov = __shfl_xor(bvv, off);
                int   oi = __shfl_xor(bii, off);
                if (ov > bvv || (ov == bvv && oi < bii)) { bvv = ov; bii = oi; }
            }
            topv[r] = bvv;
            topi[r] = bii;
            if ((bii >> 2) == lane) msk &= ~(1 << (bii & 3));
        }
        // softmax over the 8 (descending) values — every lane computes sum
        float m = topv[0];
        float s = 0.0f;
#pragma unroll
        for (int r = 0; r < TOPK; r++) s += expf(topv[r] - m);

        const int gtok = tok0 + tok;
        if (lane < TOPK) {
            out[(size_t)gtok * TOPK + lane] = expf(topv[lane] - m) / s;
        } else if (lane < 2 * TOPK) {
            int r = lane - TOPK;
            out[(size_t)TOKENS * TOPK + (size_t)gtok * TOPK + r] = (float)topi[r];
            atomicAdd(&hist[topi[r]], 1.0f);
        }
    }
    __syncthreads();
    float hv = hist[tid];
    if (hv != 0.0f) atomicAdd(&out[(size_t)2 * TOKENS * TOPK + tid], hv);
}

// ---------------- stats: std(ddof=1)/mean, max, min, expected ----------------
__global__ void k_stats(float* __restrict__ out) {
    __shared__ float sm[NEXP];
    const float* counts = out + (size_t)2 * TOKENS * TOPK;
    const int t = threadIdx.x;
    float c = counts[t];

    sm[t] = c;
    __syncthreads();
    for (int s = 128; s > 0; s >>= 1) {
        if (t < s) sm[t] += sm[t + s];
        __syncthreads();
    }
    float mean = sm[0] / (float)NEXP;
    __syncthreads();

    float d = c - mean;
    sm[t] = d * d;
    __syncthreads();
    for (int s = 128; s > 0; s >>= 1) {
        if (t < s) sm[t] += sm[t + s];
        __syncthreads();
    }
    float var = sm[0] / (float)(NEXP - 1);
    __syncthreads();

    sm[t] = c;
    __syncthreads();
    for (int s = 128; s > 0; s >>= 1) {
        if (t < s) sm[t] = fmaxf(sm[t], sm[t + s]);
        __syncthreads();
    }
    float mx = sm[0];
    __syncthreads();

    sm[t] = c;
    __syncthreads();
    for (int s = 128; s > 0; s >>= 1) {
        if (t < s) sm[t] = fminf(sm[t], sm[t + s]);
        __syncthreads();
    }
    float mn = sm[0];

    if (t == 0) {
        float* scal = out + (size_t)2 * TOKENS * TOPK + NEXP;
        scal[0] = sqrtf(var) / (mean + 1e-6f);   // load_balance
        scal[1] = mx;                            // counts.max
        scal[2] = mn;                            // counts.min
        scal[3] = (float)(TOKENS * TOPK) / (float)NEXP;  // expected_load = 512
    }
}

extern "C" void kernel_launch(void* const* d_in, const int* in_sizes, int n_in,
                              void* d_out, int out_size, void* d_ws, size_t ws_size,
                              hipStream_t stream) {
    const float* x    = (const float*)d_in[0];
    const float* w    = (const float*)d_in[1];
    const float* bias = (const float*)d_in[2];
    float* out = (float*)d_out;

    const size_t wT_bytes = (size_t)DMODEL * NEXP * sizeof(float);
    const bool use_ws = (ws_size >= wT_bytes);
    float* wT = (float*)d_ws;

    if (use_ws) {
        k_transpose<<<(DMODEL * NEXP) / 256, 256, 0, stream>>>(w, wT);
    }
    k_zero<<<1, NEXP, 0, stream>>>(out + (size_t)2 * TOKENS * TOPK);
    k_main<<<TOKENS / BM, 256, 0, stream>>>(
        x, use_ws ? wT : w, bias, out, use_ws ? 1 : 0);
    k_stats<<<1, NEXP, 0, stream>>>(out);
}